// Round 1
// baseline (122.308 us; speedup 1.0000x reference)
//
#include <hip/hip_runtime.h>
#include <math.h>

#define BDIM 256

constexpr int Bc = 2, Vc = 20000, Cc = 32, NBc = 12, KSc = 9, OUTc = 32;
constexpr int NTASK = Bc * Vc;          // 40000
constexpr int NPAIR = NTASK / 2;        // 20000 (V even -> pairs never straddle batch)
constexpr int GPB = 8;                  // 32-lane groups per 256-thread block
constexpr int WPAD = KSc * OUTc + 1;    // 289 -> bank = (lane + r) % 32, conflict-free

// ---------------- kernel 1: ux[b,v,k] = sum_c x[b,v,c] * u[c,k] ----------------
__global__ void ux_kernel(const float* __restrict__ x, const float* __restrict__ u,
                          float* __restrict__ ux)
{
    int id = blockIdx.x * blockDim.x + threadIdx.x;
    if (id >= NTASK * KSc) return;
    int bv = id / KSc;
    int k  = id - bv * KSc;
    const float* xp = x + bv * Cc;
    float acc = 0.f;
#pragma unroll
    for (int c = 0; c < Cc; ++c)
        acc = fmaf(xp[c], u[c * KSc + k], acc);
    ux[id] = acc;
}

// butterfly transpose-reduce: lane c enters with z[0..31]; lane c returns sum_{c'} z_{c'}[c]
__device__ __forceinline__ float reduce32(float (&z)[OUTc], int lane)
{
#pragma unroll
    for (int i = 0; i < 16; ++i) {
        const bool hi = (lane & 16) != 0;
        const float keep = hi ? z[i + 16] : z[i];
        const float send = hi ? z[i] : z[i + 16];
        z[i] = keep + __shfl_xor(send, 16);
    }
#pragma unroll
    for (int i = 0; i < 8; ++i) {
        const bool hi = (lane & 8) != 0;
        const float keep = hi ? z[i + 8] : z[i];
        const float send = hi ? z[i] : z[i + 8];
        z[i] = keep + __shfl_xor(send, 8);
    }
#pragma unroll
    for (int i = 0; i < 4; ++i) {
        const bool hi = (lane & 4) != 0;
        const float keep = hi ? z[i + 4] : z[i];
        const float send = hi ? z[i] : z[i + 4];
        z[i] = keep + __shfl_xor(send, 4);
    }
#pragma unroll
    for (int i = 0; i < 2; ++i) {
        const bool hi = (lane & 2) != 0;
        const float keep = hi ? z[i + 2] : z[i];
        const float send = hi ? z[i] : z[i + 2];
        z[i] = keep + __shfl_xor(send, 2);
    }
    {
        const bool hi = (lane & 1) != 0;
        const float keep = hi ? z[1] : z[0];
        const float send = hi ? z[0] : z[1];
        return keep + __shfl_xor(send, 1);
    }
}

// ---------------- kernel 2: fused softmax-aggregate-project ----------------
__global__ __launch_bounds__(BDIM, 3)
void fused_kernel(const float* __restrict__ x, const float* __restrict__ W,
                  const float* __restrict__ cvec, const float* __restrict__ bvec,
                  const int* __restrict__ adj, const float* __restrict__ ux,
                  float* __restrict__ out, int nslots)
{
    __shared__ float Wl[Cc * WPAD];        // 36992 B, padded rows
    __shared__ float qs[GPB][2][NBc][KSc]; // per-group softmax weights (2 tasks)
    __shared__ int   js[GPB][2][NBc];      // per-group neighbor row ids (-1 = pad)

    const int tid = threadIdx.x;
    for (int i = tid; i < Cc * KSc * OUTc; i += BDIM) {
        int cc = i / (KSc * OUTc);
        int rr = i - cc * (KSc * OUTc);
        Wl[cc * WPAD + rr] = W[i];
    }
    __syncthreads();   // only barrier; groups loop independently afterwards

    const int g    = tid >> 5;
    const int lane = tid & 31;
    const int slot0 = blockIdx.x * GPB + g;

    for (int pair = slot0; pair < NPAIR; pair += nslots) {
        const int t0 = pair * 2;
        const int bb = (t0 >= Vc) ? 1 : 0;

        // ---- softmax phase: lanes 0..23 cover 2 tasks x 12 neighbors ----
        bool pred = false;
        if (lane < 2 * NBc) {
            const int t    = (lane >= NBc) ? 1 : 0;
            const int n    = lane - t * NBc;
            const int task = t0 + t;
            const int v    = task - bb * Vc;
            const int j    = adj[v * NBc + n];
            pred = (j != 0);
            const int row = bb * Vc + j - 1;      // row into x / ux (valid iff pred)
            js[g][t][n] = pred ? row : -1;
            if (pred) {
                const float* uxo = ux + task * KSc;
                const float* uxn = ux + row * KSc;
                float e[KSc];
                float mx = -3.0e38f;
#pragma unroll
                for (int k = 0; k < KSc; ++k) {
                    e[k] = uxo[k] - uxn[k] + cvec[k];
                    mx = fmaxf(mx, e[k]);
                }
                float s = 0.f;
#pragma unroll
                for (int k = 0; k < KSc; ++k) { e[k] = __expf(e[k] - mx); s += e[k]; }
                const float r = 1.f / s;
#pragma unroll
                for (int k = 0; k < KSc; ++k) qs[g][t][n][k] = e[k] * r;
            }
        }
        const unsigned long long bal = __ballot(pred);
        const unsigned int mg = (tid & 32) ? (unsigned int)(bal >> 32) : (unsigned int)bal;
        const int deg0 = __popc(mg & 0xFFFu);
        const int deg1 = __popc((mg >> NBc) & 0xFFFu);
        const float inv0 = (deg0 > 0) ? 1.f / (float)deg0 : 0.f;
        const float inv1 = (deg1 > 0) ? 1.f / (float)deg1 : 0.f;

        // ---- y phase: lane c accumulates y[k] = sum_n q[n,k] * x[j_n, c] ----
        float y0[KSc], y1[KSc];
#pragma unroll
        for (int k = 0; k < KSc; ++k) { y0[k] = 0.f; y1[k] = 0.f; }
#pragma unroll
        for (int n = 0; n < NBc; ++n) {
            const int r0 = js[g][0][n];
            if (r0 >= 0) {
                const float xv = x[r0 * Cc + lane];
#pragma unroll
                for (int k = 0; k < KSc; ++k) y0[k] = fmaf(qs[g][0][n][k], xv, y0[k]);
            }
            const int r1 = js[g][1][n];
            if (r1 >= 0) {
                const float xv = x[r1 * Cc + lane];
#pragma unroll
                for (int k = 0; k < KSc; ++k) y1[k] = fmaf(qs[g][1][n][k], xv, y1[k]);
            }
        }

        // ---- z phase: z[o] = sum_k y[k] * W[c=lane, k, o] (W read once, 2 FMAs) ----
        float z0[OUTc], z1[OUTc];
#pragma unroll
        for (int o = 0; o < OUTc; ++o) { z0[o] = 0.f; z1[o] = 0.f; }
        const float* wrow = Wl + lane * WPAD;
#pragma unroll
        for (int k = 0; k < KSc; ++k) {
            const float a0 = y0[k], a1 = y1[k];
#pragma unroll
            for (int o = 0; o < OUTc; ++o) {
                const float wv = wrow[k * OUTc + o];
                z0[o] = fmaf(a0, wv, z0[o]);
                z1[o] = fmaf(a1, wv, z1[o]);
            }
        }

        // ---- cross-lane reduce over c; lane o ends with res[o] ----
        const float s0 = reduce32(z0, lane);
        const float s1 = reduce32(z1, lane);
        const float bo = bvec[lane];
        out[t0 * OUTc + lane]       = fmaxf(fmaf(inv0, s0, bo), 0.f);
        out[(t0 + 1) * OUTc + lane] = fmaxf(fmaf(inv1, s1, bo), 0.f);
    }
}

extern "C" void kernel_launch(void* const* d_in, const int* in_sizes, int n_in,
                              void* d_out, int out_size, void* d_ws, size_t ws_size,
                              hipStream_t stream)
{
    const float* x    = (const float*)d_in[0];
    const float* W    = (const float*)d_in[1];
    const float* u    = (const float*)d_in[2];
    const float* cvec = (const float*)d_in[3];
    const float* bvec = (const float*)d_in[4];
    const int*   adj  = (const int*)d_in[5];
    float* out = (float*)d_out;
    float* ux  = (float*)d_ws;   // B*V*KS floats = 1.44 MB scratch

    {
        const int total  = NTASK * KSc;
        const int blocks = (total + BDIM - 1) / BDIM;
        ux_kernel<<<blocks, BDIM, 0, stream>>>(x, u, ux);
    }
    {
        const int grid = 768;    // 3 blocks/CU at 44.7 KB LDS each
        fused_kernel<<<grid, BDIM, 0, stream>>>(x, W, cvec, bvec, adj, ux, out,
                                                grid * GPB);
    }
}